// Round 17
// baseline (147.462 us; speedup 1.0000x reference)
//
#include <hip/hip_runtime.h>
#include <cstdint>
#include <cstddef>

// Problem constants
constexpr int B = 64, S = 2048, H = 512, E = 256, V = 32000;
constexpr int NCHUNK = 64;   // attention: 64 chunks of 32 keys per batch

using bf16x8 = __attribute__((ext_vector_type(8))) short;
using f32x4  = __attribute__((ext_vector_type(4))) float;

static __device__ __forceinline__ unsigned short f2bf(float f) {
    unsigned u = __float_as_uint(f);
    u = u + 0x7fffu + ((u >> 16) & 1u);    // RNE
    return (unsigned short)(u >> 16);
}

// ---------------------------------------------------------------------------
// Kernel 1: fused scores + online-softmax partials (enc read exactly once).
// One wave per (b, 32-key chunk); proven per-key process() + prefetch
// structure; grid 1024 -> 4 blocks/CU = 16 waves/CU for BW saturation.
// ---------------------------------------------------------------------------
__global__ __launch_bounds__(256) void attn_part_kernel(
    const float* __restrict__ hd, const float* __restrict__ enc,
    float* __restrict__ m_part, float* __restrict__ l_part,
    float* __restrict__ acc_part)
{
    int b = blockIdx.x >> 4;
    int wave = threadIdx.x >> 6, lane = threadIdx.x & 63;
    int chunk = ((blockIdx.x & 15) << 2) + wave;   // 0..63
    int s0 = chunk * 32;

    const float4* hv = (const float4*)(hd + (size_t)b * H);
    float4 h0 = hv[lane], h1 = hv[64 + lane];
    const float4* ev = (const float4*)(enc + (size_t)b * S * H) + (size_t)s0 * (H / 4);

    float m = -1e30f, l = 0.f;
    float4 a0 = make_float4(0.f, 0.f, 0.f, 0.f);
    float4 a1 = make_float4(0.f, 0.f, 0.f, 0.f);
    float4 e0 = ev[lane], e1 = ev[64 + lane];

    auto process = [&](const float4& pe0, const float4& pe1) {
        float p = pe0.x * h0.x + pe0.y * h0.y + pe0.z * h0.z + pe0.w * h0.w
                + pe1.x * h1.x + pe1.y * h1.y + pe1.z * h1.z + pe1.w * h1.w;
#pragma unroll
        for (int off = 32; off; off >>= 1) p += __shfl_xor(p, off, 64);
        if (p <= m) {                 // wave-uniform branch
            float w = __expf(p - m);
            l += w;
            a0.x += w * pe0.x; a0.y += w * pe0.y; a0.z += w * pe0.z; a0.w += w * pe0.w;
            a1.x += w * pe1.x; a1.y += w * pe1.y; a1.z += w * pe1.z; a1.w += w * pe1.w;
        } else {
            float sc = __expf(m - p); // first iter: exp(-1e30)=0 -> exact init
            m = p;
            l = l * sc + 1.f;
            a0.x = a0.x * sc + pe0.x; a0.y = a0.y * sc + pe0.y;
            a0.z = a0.z * sc + pe0.z; a0.w = a0.w * sc + pe0.w;
            a1.x = a1.x * sc + pe1.x; a1.y = a1.y * sc + pe1.y;
            a1.z = a1.z * sc + pe1.z; a1.w = a1.w * sc + pe1.w;
        }
    };

    for (int s = 0; s < 31; ++s) {
        const float4* r = ev + (size_t)(s + 1) * (H / 4);
        float4 n0 = r[lane], n1 = r[64 + lane];   // prefetch next key
        process(e0, e1);                          // consume current key
        e0 = n0; e1 = n1;
    }
    process(e0, e1);                              // last key

    int base = b * NCHUNK + chunk;
    if (lane == 0) { m_part[base] = m; l_part[base] = l; }
    float4* ap = (float4*)(acc_part + (size_t)base * H);
    ap[lane] = a0; ap[64 + lane] = a1;
}

// ---------------------------------------------------------------------------
// Kernel 2 (v2): combine partials -> ctx; embedding; transposed LSTM input.
// Grid 512: block = (b, part); part owns 64 ctx dims, 4 threads/dim.
// ---------------------------------------------------------------------------
__global__ __launch_bounds__(256) void combine_kernel(
    const float* __restrict__ m_part, const float* __restrict__ l_part,
    const float* __restrict__ acc_part, const int* __restrict__ x,
    const float* __restrict__ emb, const float* __restrict__ h0,
    float* __restrict__ inp_t)
{
    const int b = blockIdx.x >> 3, part = blockIdx.x & 7, t = threadIdx.x;
    float M = -1e30f;
    for (int i = 0; i < NCHUNK; ++i) M = fmaxf(M, m_part[b * NCHUNK + i]);
    float L = 0.f;
    for (int i = 0; i < NCHUNK; ++i)
        L += l_part[b * NCHUNK + i] * __expf(m_part[b * NCHUNK + i] - M);
    const float invL = 1.f / L;

    const int d = part * 64 + (t >> 2), sub = t & 3;
    float s = 0.f;
    for (int i = sub; i < NCHUNK; i += 4)
        s += __expf(m_part[b * NCHUNK + i] - M) *
             acc_part[((size_t)(b * NCHUNK + i)) * H + d];
    s += __shfl_xor(s, 1, 64);
    s += __shfl_xor(s, 2, 64);
    if (sub == 0) inp_t[(E + d) * B + b] = s * invL;

    if (part == 0) inp_t[t * B + b] = emb[(size_t)x[b] * E + t];
    if (part == 2 || part == 3) {
        int d2 = (part - 2) * 256 + t;
        inp_t[(E + H + d2) * B + b] = h0[b * H + d2];
    }
}

// ---------------------------------------------------------------------------
// Kernel 3 (v3): fused LSTM layer, 1 unit/block, grid 512 (2 blocks/CU,
// 8 waves/CU). Conflict-free As [4][4][33] row-major (contiguous b128
// staging writes, scalar-broadcast reads). Micro 1x4 per thread.
// ---------------------------------------------------------------------------
__global__ __launch_bounds__(256) void lstm_fused_kernel(
    const float* __restrict__ A1, int lda1, int k1len,
    const float* __restrict__ A2, int lda2, int KT,
    const float* __restrict__ X,
    const float* __restrict__ b_ih, const float* __restrict__ b_hh,
    const float* __restrict__ c_prev,
    float* __restrict__ h_t, float* __restrict__ out_h, float* __restrict__ out_c,
    unsigned short* __restrict__ zbf)
{
    __shared__ float As[4][4][33];    // [quarter][gate-row][32k + pad]  2.1 KB
    __shared__ float Xs[4][32][64];   // 32 KB
    float (*Ps)[4][64] = (float(*)[4][64])&Xs[0][0][0];  // alias (4 KB)

    const int t = threadIdx.x;
    const int j = blockIdx.x;         // 1 unit/block, grid 512
    const int QK = KT >> 2;
    const int nIter = QK >> 5;
    const int kq = t >> 6, r = t & 63, ty = r >> 4, tx = r & 15;

    // A-staging: wave kq stages its quarter; threads r<32: row sg = r>>3,
    // 128B-contiguous chunk skc = r&7.
    const int sg = r >> 3, skc = r & 7;
    const int sgrow = j + 512 * sg;

    float acc[4] = {0.f, 0.f, 0.f, 0.f};

    for (int it = 0; it < nIter; ++it) {
        if (r < 32) {   // stage A: one float4, row-major, contiguous
            int gk = kq * QK + it * 32 + skc * 4;
            const float* src = (gk < k1len)
                ? A1 + (size_t)sgrow * lda1 + gk
                : A2 + (size_t)sgrow * lda2 + (gk - k1len);
            *(float4*)&As[kq][sg][skc * 4] = *(const float4*)src;
        }
#pragma unroll
        for (int q = 0; q < 8; ++q) {   // stage X (unchanged pattern)
            int p = t + q * 256;
            int kk_all = p >> 4, col = (p & 15) * 4;
            int xkq = kk_all >> 5, kk = kk_all & 31;
            int gk = xkq * QK + it * 32 + kk;
            *(float4*)&Xs[xkq][kk][col] = *(const float4*)&X[(size_t)gk * 64 + col];
        }
        __syncthreads();

#pragma unroll 8
        for (int kk = 0; kk < 32; ++kk) {
            float a = As[kq][ty][kk];
            float4 xv = *(const float4*)&Xs[kq][kk][tx * 4];
            acc[0] += a * xv.x; acc[1] += a * xv.y;
            acc[2] += a * xv.z; acc[3] += a * xv.w;
        }
        __syncthreads();
    }

    // per-quarter partials (alias Xs; all reads done)
    *(float4*)&Ps[kq][ty][tx * 4] = make_float4(acc[0], acc[1], acc[2], acc[3]);
    __syncthreads();

    // reduce 4 quarters -> Ps[0]: 256 elems, 1 per thread
    {
        int g = t >> 6, b = t & 63;
        Ps[0][g][b] = Ps[0][g][b] + Ps[1][g][b] + Ps[2][g][b] + Ps[3][g][b];
    }
    __syncthreads();

    if (t < 64) {
        int b = t;
        float gi = Ps[0][0][b] + b_ih[j]        + b_hh[j];
        float gf = Ps[0][1][b] + b_ih[j + 512]  + b_hh[j + 512];
        float gg = Ps[0][2][b] + b_ih[j + 1024] + b_hh[j + 1024];
        float go = Ps[0][3][b] + b_ih[j + 1536] + b_hh[j + 1536];
        float iv = 1.f / (1.f + __expf(-gi));
        float fv = 1.f / (1.f + __expf(-gf));
        float gv = tanhf(gg);
        float ov = 1.f / (1.f + __expf(-go));
        float cp = c_prev ? c_prev[b * H + j] : 0.f;
        float c2 = fv * cp + iv * gv;
        float hv = ov * tanhf(c2);
        h_t[j * B + b] = hv;                    // transposed for next consumer
        if (out_h) { out_h[b * H + j] = hv; out_c[b * H + j] = c2; }
        if (zbf)   { zbf[(size_t)b * H + j] = f2bf(hv); }
    }
}

// ---------------------------------------------------------------------------
// Kernel 4 (v10): fc logits via bf16 MFMA (~15 us). W LDS-staged dbuf
// (coalesced); z from global bf16 (L2-hot); split-W truncation (absmax
// unchanged at 3.8e-6).
// ---------------------------------------------------------------------------
__global__ __launch_bounds__(256) void fc_mfma_kernel(
    const float* __restrict__ A, const unsigned short* __restrict__ zbf,
    float* __restrict__ outp, const float* __restrict__ bias)
{
    __shared__ float Wt[2][64][36];   // [dbuf][row][36 words=144B], 18.4 KB

    const int t = threadIdx.x;
    const int wv  = t >> 6;
    const int l   = t & 63;
    const int row = l & 15;
    const int kq  = l >> 4;
    const int rl  = wv * 16 + row;
    const int mblk = blockIdx.x * 64;
    const int m0   = mblk + wv * 16;

    const int st_r = t >> 2, st_c = t & 3;
    const float* Asrc = A + (size_t)(mblk + st_r) * 512 + st_c * 8;

    f32x4 acc[4];
#pragma unroll
    for (int bt = 0; bt < 4; ++bt) acc[bt] = (f32x4){0.f, 0.f, 0.f, 0.f};

    {
        float4 v0 = *(const float4*)(Asrc + 0);
        float4 v1 = *(const float4*)(Asrc + 4);
        *(float4*)&Wt[0][st_r][st_c * 8]     = v0;
        *(float4*)&Wt[0][st_r][st_c * 8 + 4] = v1;
    }
    __syncthreads();

    for (int s = 0; s < 16; ++s) {
        const int buf = s & 1;
        if (s < 15) {
            const float* src = Asrc + (s + 1) * 32;
            float4 v0 = *(const float4*)(src + 0);
            float4 v1 = *(const float4*)(src + 4);
            *(float4*)&Wt[buf ^ 1][st_r][st_c * 8]     = v0;
            *(float4*)&Wt[buf ^ 1][st_r][st_c * 8 + 4] = v1;
        }

        const float* wrow = &Wt[buf][rl][kq * 8];
        float4 wa = *(const float4*)wrow;
        float4 wb = *(const float4*)(wrow + 4);
        float wf[8] = {wa.x, wa.y, wa.z, wa.w, wb.x, wb.y, wb.z, wb.w};

        unsigned hd[4], ld[4];
#pragma unroll
        for (int p = 0; p < 4; ++p) {
            unsigned u0 = __float_as_uint(wf[2 * p]);
            unsigned u1 = __float_as_uint(wf[2 * p + 1]);
            hd[p] = (u0 >> 16) | (u1 & 0xffff0000u);
            float r0 = wf[2 * p]     - __uint_as_float(u0 & 0xffff0000u);
            float r1 = wf[2 * p + 1] - __uint_as_float(u1 & 0xffff0000u);
            ld[p] = (__float_as_uint(r0) >> 16) | (__float_as_uint(r1) & 0xffff0000u);
        }
        union { uint4 u; bf16x8 v; } cvh, cvl;
        cvh.u = make_uint4(hd[0], hd[1], hd[2], hd[3]);
        cvl.u = make_uint4(ld[0], ld[1], ld[2], ld[3]);

        const int kgl = s * 32 + kq * 8;
#pragma unroll
        for (int bt = 0; bt < 4; ++bt) {
            int b = bt * 16 + row;
            bf16x8 zf = *(const bf16x8*)(zbf + (size_t)b * 512 + kgl);
            acc[bt] = __builtin_amdgcn_mfma_f32_16x16x32_bf16(cvh.v, zf, acc[bt], 0, 0, 0);
            acc[bt] = __builtin_amdgcn_mfma_f32_16x16x32_bf16(cvl.v, zf, acc[bt], 0, 0, 0);
        }
        __syncthreads();
    }

    int v0 = m0 + kq * 4;
    float4 bv = *(const float4*)&bias[v0];
#pragma unroll
    for (int bt = 0; bt < 4; ++bt) {
        int b = bt * 16 + row;
        float4 o;
        o.x = acc[bt][0] + bv.x;
        o.y = acc[bt][1] + bv.y;
        o.z = acc[bt][2] + bv.z;
        o.w = acc[bt][3] + bv.w;
        *(float4*)&outp[(size_t)b * V + v0] = o;
    }
}

// ---------------------------------------------------------------------------
extern "C" void kernel_launch(void* const* d_in, const int* in_sizes, int n_in,
                              void* d_out, int out_size, void* d_ws, size_t ws_size,
                              hipStream_t stream)
{
    const int*   x     = (const int*)d_in[0];
    const float* hdec  = (const float*)d_in[1];
    const float* enc   = (const float*)d_in[2];
    const float* h0    = (const float*)d_in[3];
    const float* c0    = (const float*)d_in[4];
    const float* emb   = (const float*)d_in[5];
    const float* w_ih1 = (const float*)d_in[6];
    const float* w_hh1 = (const float*)d_in[7];
    const float* b_ih1 = (const float*)d_in[8];
    const float* b_hh1 = (const float*)d_in[9];
    const float* w_ih  = (const float*)d_in[10];
    // d_in[11] = w_hh: multiplied by zero hidden state in layers 2-4 -> skipped
    const float* b_ih  = (const float*)d_in[12];
    const float* b_hh  = (const float*)d_in[13];
    const float* fc_w  = (const float*)d_in[14];
    const float* fc_b  = (const float*)d_in[15];

    float* out = (float*)d_out;
    float* ws  = (float*)d_ws;

    float* m_part   = ws;                                // 4096
    float* l_part   = ws + 4096;                         // 4096
    float* acc_part = ws + 8192;                         // 64*64*512
    float* inp_t    = acc_part + (size_t)B * NCHUNK * H; // 1280*64
    float* zA       = inp_t + 1280 * B;                  // 512*64
    float* zB       = zA + H * B;                        // 512*64
    unsigned short* zbf = (unsigned short*)(zB + H * B); // 64*512 bf16 (64 KB)

    float* out_h = out + (size_t)B * V;
    float* out_c = out_h + (size_t)B * H;

    // 1) attention (enc read once, 268 MB); 1024 blocks = 16 waves/CU
    attn_part_kernel<<<1024, 256, 0, stream>>>(hdec, enc, m_part, l_part, acc_part);
    combine_kernel<<<512, 256, 0, stream>>>(m_part, l_part, acc_part, x, emb, h0, inp_t);

    // 2) LSTM layer 1: K = 768 (w_ih1) | 512 (w_hh1) = 1280, real c0
    lstm_fused_kernel<<<512, 256, 0, stream>>>(
        w_ih1, 768, 768, w_hh1, 512, 1280, inp_t,
        b_ih1, b_hh1, c0, zA, nullptr, nullptr, nullptr);

    // 3) LSTM layers 2-4 (zero h/c: only w_ih contributes), K = 512
    lstm_fused_kernel<<<512, 256, 0, stream>>>(
        w_ih + 0 * (size_t)2048 * H, 512, 512, nullptr, 0, 512, zA,
        b_ih + 0 * 2048, b_hh + 0 * 2048, nullptr, zB, nullptr, nullptr, nullptr);
    lstm_fused_kernel<<<512, 256, 0, stream>>>(
        w_ih + 1 * (size_t)2048 * H, 512, 512, nullptr, 0, 512, zB,
        b_ih + 1 * 2048, b_hh + 1 * 2048, nullptr, zA, nullptr, nullptr, nullptr);
    lstm_fused_kernel<<<512, 256, 0, stream>>>(
        w_ih + 2 * (size_t)2048 * H, 512, 512, nullptr, 0, 512, zA,
        b_ih + 2 * 2048, b_hh + 2 * 2048, nullptr, zB, out_h, out_c, zbf);

    // 4) logits = zbf @ fc_w^T + fc_b  (MFMA; W LDS-staged, z bf16 from L2)
    fc_mfma_kernel<<<500, 256, 0, stream>>>(fc_w, zbf, out, fc_b);
}

// Round 18
// 135.447 us; speedup vs baseline: 1.0887x; 1.0887x over previous
//
#include <hip/hip_runtime.h>
#include <cstdint>
#include <cstddef>

// Problem constants
constexpr int B = 64, S = 2048, H = 512, E = 256, V = 32000;
constexpr int NCHUNK = 32;   // attention: 32 chunks of 64 keys per batch

using bf16x8 = __attribute__((ext_vector_type(8))) short;
using f32x4  = __attribute__((ext_vector_type(4))) float;

static __device__ __forceinline__ unsigned short f2bf(float f) {
    unsigned u = __float_as_uint(f);
    u = u + 0x7fffu + ((u >> 16) & 1u);    // RNE
    return (unsigned short)(u >> 16);
}

// ---------------------------------------------------------------------------
// Kernel 1 (pairwise): fused scores + online-softmax partials.
// One wave per (b, 64-key chunk). Keys processed in PAIRS: two independent
// 6-deep shuffle chains interleaved (latency overlap), one combined
// max/rescale per pair (exact online softmax with block=2). Same bytes,
// same FMA count, half the serial branch/exp/rescale overhead vs R16.
// ---------------------------------------------------------------------------
__global__ __launch_bounds__(256) void attn_part_kernel(
    const float* __restrict__ hd, const float* __restrict__ enc,
    float* __restrict__ m_part, float* __restrict__ l_part,
    float* __restrict__ acc_part)
{
    int b = blockIdx.x >> 3;
    int wave = threadIdx.x >> 6, lane = threadIdx.x & 63;
    int chunk = ((blockIdx.x & 7) << 2) + wave;
    int s0 = chunk * 64;

    const float4* hv = (const float4*)(hd + (size_t)b * H);
    float4 h0 = hv[lane], h1 = hv[64 + lane];
    const float4* ev = (const float4*)(enc + (size_t)b * S * H) + (size_t)s0 * (H / 4);

    float m = -1e30f, l = 0.f;
    float4 a0 = make_float4(0.f, 0.f, 0.f, 0.f);
    float4 a1 = make_float4(0.f, 0.f, 0.f, 0.f);

    // current pair: keys 2s (e0,e1) and 2s+1 (f0,f1)
    float4 e0 = ev[lane], e1 = ev[64 + lane];
    float4 f0 = ev[128 + lane], f1 = ev[192 + lane];

    for (int s = 0; s < 32; ++s) {
        // prefetch next pair (clamped on last iter; discarded)
        const float4* r = ev + (size_t)(s < 31 ? 2 * s + 2 : 0) * (H / 4);
        float4 n0 = r[lane], n1 = r[64 + lane];
        float4 g0 = r[128 + lane], g1 = r[192 + lane];

        float p1 = e0.x * h0.x + e0.y * h0.y + e0.z * h0.z + e0.w * h0.w
                 + e1.x * h1.x + e1.y * h1.y + e1.z * h1.z + e1.w * h1.w;
        float p2 = f0.x * h0.x + f0.y * h0.y + f0.z * h0.z + f0.w * h0.w
                 + f1.x * h1.x + f1.y * h1.y + f1.z * h1.z + f1.w * h1.w;
#pragma unroll
        for (int off = 32; off; off >>= 1) {    // two independent chains,
            p1 += __shfl_xor(p1, off, 64);      // interleaved for ILP
            p2 += __shfl_xor(p2, off, 64);
        }

        float bm = fmaxf(p1, p2);
        if (bm <= m) {                          // wave-uniform branch
            float w1 = __expf(p1 - m), w2 = __expf(p2 - m);
            l += w1 + w2;
            a0.x += w1 * e0.x + w2 * f0.x; a0.y += w1 * e0.y + w2 * f0.y;
            a0.z += w1 * e0.z + w2 * f0.z; a0.w += w1 * e0.w + w2 * f0.w;
            a1.x += w1 * e1.x + w2 * f1.x; a1.y += w1 * e1.y + w2 * f1.y;
            a1.z += w1 * e1.z + w2 * f1.z; a1.w += w1 * e1.w + w2 * f1.w;
        } else {
            float sc = __expf(m - bm);          // first pair: exp(-inf)=0 exact
            m = bm;
            float w1 = __expf(p1 - bm), w2 = __expf(p2 - bm);
            l = l * sc + w1 + w2;
            a0.x = a0.x * sc + w1 * e0.x + w2 * f0.x;
            a0.y = a0.y * sc + w1 * e0.y + w2 * f0.y;
            a0.z = a0.z * sc + w1 * e0.z + w2 * f0.z;
            a0.w = a0.w * sc + w1 * e0.w + w2 * f0.w;
            a1.x = a1.x * sc + w1 * e1.x + w2 * f1.x;
            a1.y = a1.y * sc + w1 * e1.y + w2 * f1.y;
            a1.z = a1.z * sc + w1 * e1.z + w2 * f1.z;
            a1.w = a1.w * sc + w1 * e1.w + w2 * f1.w;
        }
        e0 = n0; e1 = n1; f0 = g0; f1 = g1;
    }

    int base = b * NCHUNK + chunk;
    if (lane == 0) { m_part[base] = m; l_part[base] = l; }
    float4* ap = (float4*)(acc_part + (size_t)base * H);
    ap[lane] = a0; ap[64 + lane] = a1;
}

// ---------------------------------------------------------------------------
// Kernel 2: combine partials -> ctx; embedding gather; transposed LSTM input
// inp_t[k][b]: [0,256)=xe, [256,768)=ctx, [768,1280)=h0.  (R16 version)
// ---------------------------------------------------------------------------
__global__ __launch_bounds__(256) void combine_kernel(
    const float* __restrict__ m_part, const float* __restrict__ l_part,
    const float* __restrict__ acc_part, const int* __restrict__ x,
    const float* __restrict__ emb, const float* __restrict__ h0,
    float* __restrict__ inp_t)
{
    int b = blockIdx.x, t = threadIdx.x;
    float M = -1e30f;
    for (int i = 0; i < NCHUNK; ++i) M = fmaxf(M, m_part[b * NCHUNK + i]);
    float L = 0.f;
    for (int i = 0; i < NCHUNK; ++i)
        L += l_part[b * NCHUNK + i] * __expf(m_part[b * NCHUNK + i] - M);
    float invL = 1.f / L;

    for (int d = t; d < H; d += 256) {
        float s = 0.f;
        for (int i = 0; i < NCHUNK; ++i)
            s += __expf(m_part[b * NCHUNK + i] - M) *
                 acc_part[((size_t)(b * NCHUNK + i)) * H + d];
        inp_t[(E + d) * B + b] = s * invL;
    }
    inp_t[t * B + b] = emb[(size_t)x[b] * E + t];
    for (int d = t; d < H; d += 256)
        inp_t[(E + H + d) * B + b] = h0[b * H + d];
}

// ---------------------------------------------------------------------------
// Kernel 3 (v2, R16): fused LSTM layer, conflict-free + full-chip grid.
// 2 units/block (8 A-rows: row il = unit(il&1)+2*gate(il>>1)), grid 256.
// As ROW-MAJOR [4][8][33]: contiguous b128 staging writes; scalar-broadcast
// fragment reads. Wave kq owns its K-quarter. Micro 2x4 per thread.
// ---------------------------------------------------------------------------
__global__ __launch_bounds__(256) void lstm_fused_kernel(
    const float* __restrict__ A1, int lda1, int k1len,
    const float* __restrict__ A2, int lda2, int KT,
    const float* __restrict__ X,
    const float* __restrict__ b_ih, const float* __restrict__ b_hh,
    const float* __restrict__ c_prev,
    float* __restrict__ h_t, float* __restrict__ out_h, float* __restrict__ out_c,
    unsigned short* __restrict__ zbf)
{
    __shared__ float As[4][8][33];    // [quarter][row][32k + 1 pad]  4.2 KB
    __shared__ float Xs[4][32][64];   // 32 KB
    float (*Ps)[8][64] = (float(*)[8][64])&Xs[0][0][0];  // alias (8 KB)

    const int t = threadIdx.x;
    const int j0 = blockIdx.x * 2;    // 2 units/block, grid 256
    const int QK = KT >> 2;
    const int nIter = QK >> 5;
    const int kq = t >> 6, r = t & 63, ty = r >> 4, tx = r & 15;

    const int sil = (t >> 3) & 7, skc = t & 7;
    const int sgrow = j0 + (sil & 1) + 512 * (sil >> 1);

    float acc[2][4];
#pragma unroll
    for (int i = 0; i < 2; ++i)
#pragma unroll
        for (int j = 0; j < 4; ++j) acc[i][j] = 0.f;

    for (int it = 0; it < nIter; ++it) {
        {   // stage A: one float4 per thread, row-major, contiguous write
            int gk = kq * QK + it * 32 + skc * 4;
            const float* src = (gk < k1len)
                ? A1 + (size_t)sgrow * lda1 + gk
                : A2 + (size_t)sgrow * lda2 + (gk - k1len);
            *(float4*)&As[kq][sil][skc * 4] = *(const float4*)src;
        }
#pragma unroll
        for (int q = 0; q < 8; ++q) {   // stage X
            int p = t + q * 256;
            int kk_all = p >> 4, col = (p & 15) * 4;
            int xkq = kk_all >> 5, kk = kk_all & 31;
            int gk = xkq * QK + it * 32 + kk;
            *(float4*)&Xs[xkq][kk][col] = *(const float4*)&X[(size_t)gk * 64 + col];
        }
        __syncthreads();

#pragma unroll 8
        for (int kk = 0; kk < 32; ++kk) {
            float a0 = As[kq][2 * ty + 0][kk];
            float a1 = As[kq][2 * ty + 1][kk];
            float4 xv = *(const float4*)&Xs[kq][kk][tx * 4];
            float xx[4] = {xv.x, xv.y, xv.z, xv.w};
#pragma unroll
            for (int j = 0; j < 4; ++j) {
                acc[0][j] += a0 * xx[j];
                acc[1][j] += a1 * xx[j];
            }
        }
        __syncthreads();
    }

#pragma unroll
    for (int i = 0; i < 2; ++i)
        *(float4*)&Ps[kq][2 * ty + i][tx * 4] =
            make_float4(acc[i][0], acc[i][1], acc[i][2], acc[i][3]);
    __syncthreads();

    for (int idx = t; idx < 8 * 64; idx += 256) {
        int row = idx >> 6, b = idx & 63;
        Ps[0][row][b] = Ps[0][row][b] + Ps[1][row][b] + Ps[2][row][b] + Ps[3][row][b];
    }
    __syncthreads();

    if (t < 128) {
        int jj = t >> 6, b = t & 63;
        int j = j0 + jj;
        float gi = Ps[0][jj + 0][b] + b_ih[j]        + b_hh[j];
        float gf = Ps[0][jj + 2][b] + b_ih[j + 512]  + b_hh[j + 512];
        float gg = Ps[0][jj + 4][b] + b_ih[j + 1024] + b_hh[j + 1024];
        float go = Ps[0][jj + 6][b] + b_ih[j + 1536] + b_hh[j + 1536];
        float iv = 1.f / (1.f + __expf(-gi));
        float fv = 1.f / (1.f + __expf(-gf));
        float gv = tanhf(gg);
        float ov = 1.f / (1.f + __expf(-go));
        float cp = c_prev ? c_prev[b * H + j] : 0.f;
        float c2 = fv * cp + iv * gv;
        float hv = ov * tanhf(c2);
        h_t[j * B + b] = hv;                    // transposed for next consumer
        if (out_h) { out_h[b * H + j] = hv; out_c[b * H + j] = c2; }
        if (zbf)   { zbf[(size_t)b * H + j] = f2bf(hv); }
    }
}

// ---------------------------------------------------------------------------
// Kernel 4 (v10, R16): fc logits via bf16 MFMA (~15 us). W LDS-staged dbuf
// (coalesced); z from global bf16 (L2-hot); split-W truncation.
// ---------------------------------------------------------------------------
__global__ __launch_bounds__(256) void fc_mfma_kernel(
    const float* __restrict__ A, const unsigned short* __restrict__ zbf,
    float* __restrict__ outp, const float* __restrict__ bias)
{
    __shared__ float Wt[2][64][36];   // [dbuf][row][36 words=144B], 18.4 KB

    const int t = threadIdx.x;
    const int wv  = t >> 6;
    const int l   = t & 63;
    const int row = l & 15;
    const int kq  = l >> 4;
    const int rl  = wv * 16 + row;
    const int mblk = blockIdx.x * 64;
    const int m0   = mblk + wv * 16;

    const int st_r = t >> 2, st_c = t & 3;
    const float* Asrc = A + (size_t)(mblk + st_r) * 512 + st_c * 8;

    f32x4 acc[4];
#pragma unroll
    for (int bt = 0; bt < 4; ++bt) acc[bt] = (f32x4){0.f, 0.f, 0.f, 0.f};

    {
        float4 v0 = *(const float4*)(Asrc + 0);
        float4 v1 = *(const float4*)(Asrc + 4);
        *(float4*)&Wt[0][st_r][st_c * 8]     = v0;
        *(float4*)&Wt[0][st_r][st_c * 8 + 4] = v1;
    }
    __syncthreads();

    for (int s = 0; s < 16; ++s) {
        const int buf = s & 1;
        if (s < 15) {
            const float* src = Asrc + (s + 1) * 32;
            float4 v0 = *(const float4*)(src + 0);
            float4 v1 = *(const float4*)(src + 4);
            *(float4*)&Wt[buf ^ 1][st_r][st_c * 8]     = v0;
            *(float4*)&Wt[buf ^ 1][st_r][st_c * 8 + 4] = v1;
        }

        const float* wrow = &Wt[buf][rl][kq * 8];
        float4 wa = *(const float4*)wrow;
        float4 wb = *(const float4*)(wrow + 4);
        float wf[8] = {wa.x, wa.y, wa.z, wa.w, wb.x, wb.y, wb.z, wb.w};

        unsigned hd[4], ld[4];
#pragma unroll
        for (int p = 0; p < 4; ++p) {
            unsigned u0 = __float_as_uint(wf[2 * p]);
            unsigned u1 = __float_as_uint(wf[2 * p + 1]);
            hd[p] = (u0 >> 16) | (u1 & 0xffff0000u);
            float r0 = wf[2 * p]     - __uint_as_float(u0 & 0xffff0000u);
            float r1 = wf[2 * p + 1] - __uint_as_float(u1 & 0xffff0000u);
            ld[p] = (__float_as_uint(r0) >> 16) | (__float_as_uint(r1) & 0xffff0000u);
        }
        union { uint4 u; bf16x8 v; } cvh, cvl;
        cvh.u = make_uint4(hd[0], hd[1], hd[2], hd[3]);
        cvl.u = make_uint4(ld[0], ld[1], ld[2], ld[3]);

        const int kgl = s * 32 + kq * 8;
#pragma unroll
        for (int bt = 0; bt < 4; ++bt) {
            int b = bt * 16 + row;
            bf16x8 zf = *(const bf16x8*)(zbf + (size_t)b * 512 + kgl);
            acc[bt] = __builtin_amdgcn_mfma_f32_16x16x32_bf16(cvh.v, zf, acc[bt], 0, 0, 0);
            acc[bt] = __builtin_amdgcn_mfma_f32_16x16x32_bf16(cvl.v, zf, acc[bt], 0, 0, 0);
        }
        __syncthreads();
    }

    int v0 = m0 + kq * 4;
    float4 bv = *(const float4*)&bias[v0];
#pragma unroll
    for (int bt = 0; bt < 4; ++bt) {
        int b = bt * 16 + row;
        float4 o;
        o.x = acc[bt][0] + bv.x;
        o.y = acc[bt][1] + bv.y;
        o.z = acc[bt][2] + bv.z;
        o.w = acc[bt][3] + bv.w;
        *(float4*)&outp[(size_t)b * V + v0] = o;
    }
}

// ---------------------------------------------------------------------------
extern "C" void kernel_launch(void* const* d_in, const int* in_sizes, int n_in,
                              void* d_out, int out_size, void* d_ws, size_t ws_size,
                              hipStream_t stream)
{
    const int*   x     = (const int*)d_in[0];
    const float* hdec  = (const float*)d_in[1];
    const float* enc   = (const float*)d_in[2];
    const float* h0    = (const float*)d_in[3];
    const float* c0    = (const float*)d_in[4];
    const float* emb   = (const float*)d_in[5];
    const float* w_ih1 = (const float*)d_in[6];
    const float* w_hh1 = (const float*)d_in[7];
    const float* b_ih1 = (const float*)d_in[8];
    const float* b_hh1 = (const float*)d_in[9];
    const float* w_ih  = (const float*)d_in[10];
    // d_in[11] = w_hh: multiplied by zero hidden state in layers 2-4 -> skipped
    const float* b_ih  = (const float*)d_in[12];
    const float* b_hh  = (const float*)d_in[13];
    const float* fc_w  = (const float*)d_in[14];
    const float* fc_b  = (const float*)d_in[15];

    float* out = (float*)d_out;
    float* ws  = (float*)d_ws;

    float* m_part   = ws;                                // 2048
    float* l_part   = ws + 2048;                         // 2048
    float* acc_part = ws + 4096;                         // 64*32*512
    float* inp_t    = acc_part + (size_t)B * NCHUNK * H; // 1280*64
    float* zA       = inp_t + 1280 * B;                  // 512*64
    float* zB       = zA + H * B;                        // 512*64
    unsigned short* zbf = (unsigned short*)(zB + H * B); // 64*512 bf16 (64 KB)

    float* out_h = out + (size_t)B * V;
    float* out_c = out_h + (size_t)B * H;

    // 1) attention (enc read once, 268 MB); pairwise online softmax
    attn_part_kernel<<<512, 256, 0, stream>>>(hdec, enc, m_part, l_part, acc_part);
    combine_kernel<<<64, 256, 0, stream>>>(m_part, l_part, acc_part, x, emb, h0, inp_t);

    // 2) LSTM layer 1: K = 768 (w_ih1) | 512 (w_hh1) = 1280, real c0
    lstm_fused_kernel<<<256, 256, 0, stream>>>(
        w_ih1, 768, 768, w_hh1, 512, 1280, inp_t,
        b_ih1, b_hh1, c0, zA, nullptr, nullptr, nullptr);

    // 3) LSTM layers 2-4 (zero h/c: only w_ih contributes), K = 512
    lstm_fused_kernel<<<256, 256, 0, stream>>>(
        w_ih + 0 * (size_t)2048 * H, 512, 512, nullptr, 0, 512, zA,
        b_ih + 0 * 2048, b_hh + 0 * 2048, nullptr, zB, nullptr, nullptr, nullptr);
    lstm_fused_kernel<<<256, 256, 0, stream>>>(
        w_ih + 1 * (size_t)2048 * H, 512, 512, nullptr, 0, 512, zB,
        b_ih + 1 * 2048, b_hh + 1 * 2048, nullptr, zA, nullptr, nullptr, nullptr);
    lstm_fused_kernel<<<256, 256, 0, stream>>>(
        w_ih + 2 * (size_t)2048 * H, 512, 512, nullptr, 0, 512, zA,
        b_ih + 2 * 2048, b_hh + 2 * 2048, nullptr, zB, out_h, out_c, zbf);

    // 4) logits = zbf @ fc_w^T + fc_b  (MFMA; W LDS-staged, z bf16 from L2)
    fc_mfma_kernel<<<500, 256, 0, stream>>>(fc_w, zbf, out, fc_b);
}